// Round 7
// baseline (14.225 us; speedup 1.0000x reference)
//
#include <hip/hip_runtime.h>

#define BLK 256
#define SPT 4               // samples per thread
#define SPB (BLK * SPT)     // 1024 samples per block

typedef float f32x4 __attribute__((ext_vector_type(4)));

__global__ __launch_bounds__(BLK) void dlt_solve_kernel(
    const float* __restrict__ corners,  // (8, B): [comp*B + i], comp = k*2 + {0:y,1:x}
    const float* __restrict__ h4pt,     // (B, 8)
    float* __restrict__ out,            // (B, 9) -> (B,3,3)
    int B)
{
    __shared__ __align__(16) float sout[SPB * 9];   // 36 KB
    const int tid = threadIdx.x;
    const int i0 = blockIdx.x * SPB + tid * SPT;    // first of SPT consecutive samples

    if (i0 + SPT <= B) {
        // ---- vectorized loads: 16 B/lane everywhere ----
        f32x4 c4[8];
#pragma unroll
        for (int comp = 0; comp < 8; ++comp)
            c4[comp] = *reinterpret_cast<const f32x4*>(corners + (size_t)comp * B + i0);

        const f32x4* h4 = reinterpret_cast<const f32x4*>(h4pt + (size_t)i0 * 8);
        f32x4 hv[8];
#pragma unroll
        for (int j = 0; j < 8; ++j) hv[j] = h4[j];

#pragma unroll
        for (int s = 0; s < SPT; ++s) {
            float dy[4] = {hv[2 * s].x, hv[2 * s].z, hv[2 * s + 1].x, hv[2 * s + 1].z};
            float dx[4] = {hv[2 * s].y, hv[2 * s].w, hv[2 * s + 1].y, hv[2 * s + 1].w};

            float ya[4], xa[4], yb[4], xb[4];
#pragma unroll
            for (int k = 0; k < 4; ++k) {
                ya[k] = c4[2 * k][s];        // s is compile-time (unrolled)
                xa[k] = c4[2 * k + 1][s];
                yb[k] = ya[k] + dy[k];
                xb[k] = xa[k] + dx[k];
            }

            // left null-vector of M = [[ya_k, xa_k, 1]] (4x3)
            auto D3 = [&](int a, int b, int c) {
                return (ya[b] - ya[a]) * (xa[c] - xa[a]) - (ya[c] - ya[a]) * (xa[b] - xa[a]);
            };
            float D012 = D3(0, 1, 2);
            float nn[4];
            nn[0] =  D3(1, 2, 3);
            nn[1] = -D3(0, 2, 3);
            nn[2] =  D3(0, 1, 3);
            nn[3] = -D012;

            // 2x2 system for (h6, h7)
            float a00 = 0.f, a01 = 0.f, r0 = 0.f;
            float a10 = 0.f, a11 = 0.f, r1 = 0.f;
#pragma unroll
            for (int k = 0; k < 4; ++k) {
                float tx = nn[k] * xb[k];
                float ty = nn[k] * yb[k];
                a00 = fmaf(tx, ya[k], a00);
                a01 = fmaf(tx, xa[k], a01);
                r0 -= tx;
                a10 = fmaf(ty, ya[k], a10);
                a11 = fmaf(ty, xa[k], a11);
                r1 -= ty;
            }
            float inv2 = 1.0f / (a00 * a11 - a01 * a10);
            float h6 = (r0 * a11 - a01 * r1) * inv2;
            float h7 = (a00 * r1 - r0 * a10) * inv2;

            // Cramer back-solve for u,v from rows {0,1,2}
            float s0 = fmaf(ya[0], h6, fmaf(xa[0], h7, 1.0f));
            float s1 = fmaf(ya[1], h6, fmaf(xa[1], h7, 1.0f));
            float s2 = fmaf(ya[2], h6, fmaf(xa[2], h7, 1.0f));
            float ru0 = yb[0] * s0, ru1 = yb[1] * s1, ru2 = yb[2] * s2;
            float rv0 = xb[0] * s0, rv1 = xb[1] * s1, rv2 = xb[2] * s2;

            float dy1 = ya[1] - ya[0], dy2 = ya[2] - ya[0];
            float dx1 = xa[1] - xa[0], dx2 = xa[2] - xa[0];
            float g0 = ya[1] * xa[2] - ya[2] * xa[1];
            float g1 = ya[0] * xa[2] - ya[2] * xa[0];
            float g2 = ya[0] * xa[1] - ya[1] * xa[0];
            float inv3 = 1.0f / D012;

            float du1 = ru1 - ru0, du2 = ru2 - ru0;
            float dv1 = rv1 - rv0, dv2 = rv2 - rv0;

            float* so = sout + tid * (SPT * 9) + s * 9;
            so[0] = (du1 * dx2 - du2 * dx1) * inv3;
            so[1] = (dy1 * du2 - dy2 * du1) * inv3;
            so[2] = (ru0 * g0 - ru1 * g1 + ru2 * g2) * inv3;
            so[3] = (dv1 * dx2 - dv2 * dx1) * inv3;
            so[4] = (dy1 * dv2 - dy2 * dv1) * inv3;
            so[5] = (rv0 * g0 - rv1 * g1 + rv2 * g2) * inv3;
            so[6] = h6;
            so[7] = h7;
            so[8] = 1.0f;
        }
    } else {
        // tail (only when B % SPB != 0)
#pragma unroll
        for (int v = 0; v < SPT * 9; ++v) sout[tid * (SPT * 9) + v] = 0.f;
    }
    __syncthreads();

    const size_t base = (size_t)blockIdx.x * SPB * 9;  // floats
    const size_t total = (size_t)B * 9;
    if (base + (size_t)SPB * 9 <= total) {
        f32x4* out4 = reinterpret_cast<f32x4*>(out + base);
        const f32x4* s4 = reinterpret_cast<const f32x4*>(sout);
        constexpr int NV = SPB * 9 / 4;  // 2304
#pragma unroll
        for (int v = tid; v < NV; v += BLK) out4[v] = s4[v];
    } else {
        for (int v = tid; v < SPB * 9; v += BLK) {
            size_t g = base + v;
            if (g < total) out[g] = sout[v];
        }
    }
}

extern "C" void kernel_launch(void* const* d_in, const int* in_sizes, int n_in,
                              void* d_out, int out_size, void* d_ws, size_t ws_size,
                              hipStream_t stream) {
    const float* corners = (const float*)d_in[0];  // (8, B) float32
    const float* h4pt    = (const float*)d_in[1];  // (B, 8) float32
    float* out = (float*)d_out;                    // (B, 3, 3) float32
    const int B = in_sizes[0] / 8;
    const int grid = (B + SPB - 1) / SPB;
    dlt_solve_kernel<<<grid, BLK, 0, stream>>>(corners, h4pt, out, B);
}

// Round 8
// 12.597 us; speedup vs baseline: 1.1292x; 1.1292x over previous
//
#include <hip/hip_runtime.h>

#define BLK 256
#define SPT 2               // samples per thread
#define SPB (BLK * SPT)     // 512 samples per block

typedef float f32x2 __attribute__((ext_vector_type(2)));
typedef float f32x4 __attribute__((ext_vector_type(4)));

__global__ __launch_bounds__(BLK) void dlt_solve_kernel(
    const float* __restrict__ corners,  // (8, B): [comp*B + i], comp = k*2 + {0:y,1:x}
    const float* __restrict__ h4pt,     // (B, 8)
    float* __restrict__ out,            // (B, 9) -> (B,3,3)
    int B)
{
    __shared__ __align__(16) float sout[SPB * 9];   // 18 KB, wave-private regions
    const int tid  = threadIdx.x;
    const int lane = tid & 63;
    const int w    = tid >> 6;                      // wave id within block
    const int i0 = blockIdx.x * SPB + tid * SPT;    // first of SPT consecutive samples

    if (i0 + SPT <= B) {
        // ---- vectorized plain loads ----
        f32x2 c2[8];
#pragma unroll
        for (int comp = 0; comp < 8; ++comp)
            c2[comp] = *reinterpret_cast<const f32x2*>(corners + (size_t)comp * B + i0);

        const f32x4* h4 = reinterpret_cast<const f32x4*>(h4pt + (size_t)i0 * 8);
        f32x4 hv[4];
#pragma unroll
        for (int j = 0; j < 4; ++j) hv[j] = h4[j];

#pragma unroll
        for (int s = 0; s < SPT; ++s) {
            float dy[4] = {hv[2 * s].x, hv[2 * s].z, hv[2 * s + 1].x, hv[2 * s + 1].z};
            float dx[4] = {hv[2 * s].y, hv[2 * s].w, hv[2 * s + 1].y, hv[2 * s + 1].w};

            float ya[4], xa[4], yb[4], xb[4];
#pragma unroll
            for (int k = 0; k < 4; ++k) {
                ya[k] = (s == 0) ? c2[2 * k].x : c2[2 * k].y;
                xa[k] = (s == 0) ? c2[2 * k + 1].x : c2[2 * k + 1].y;
                yb[k] = ya[k] + dy[k];
                xb[k] = xa[k] + dx[k];
            }

            // left null-vector of M = [[ya_k, xa_k, 1]] (4x3)
            auto D3 = [&](int a, int b, int c) {
                return (ya[b] - ya[a]) * (xa[c] - xa[a]) - (ya[c] - ya[a]) * (xa[b] - xa[a]);
            };
            float D012 = D3(0, 1, 2);
            float nn[4];
            nn[0] =  D3(1, 2, 3);
            nn[1] = -D3(0, 2, 3);
            nn[2] =  D3(0, 1, 3);
            nn[3] = -D012;

            // 2x2 system for (h6, h7)
            float a00 = 0.f, a01 = 0.f, r0 = 0.f;
            float a10 = 0.f, a11 = 0.f, r1 = 0.f;
#pragma unroll
            for (int k = 0; k < 4; ++k) {
                float tx = nn[k] * xb[k];
                float ty = nn[k] * yb[k];
                a00 = fmaf(tx, ya[k], a00);
                a01 = fmaf(tx, xa[k], a01);
                r0 -= tx;
                a10 = fmaf(ty, ya[k], a10);
                a11 = fmaf(ty, xa[k], a11);
                r1 -= ty;
            }
            float inv2 = 1.0f / (a00 * a11 - a01 * a10);
            float h6 = (r0 * a11 - a01 * r1) * inv2;
            float h7 = (a00 * r1 - r0 * a10) * inv2;

            // Cramer back-solve for u,v from rows {0,1,2}
            float s0 = fmaf(ya[0], h6, fmaf(xa[0], h7, 1.0f));
            float s1 = fmaf(ya[1], h6, fmaf(xa[1], h7, 1.0f));
            float s2 = fmaf(ya[2], h6, fmaf(xa[2], h7, 1.0f));
            float ru0 = yb[0] * s0, ru1 = yb[1] * s1, ru2 = yb[2] * s2;
            float rv0 = xb[0] * s0, rv1 = xb[1] * s1, rv2 = xb[2] * s2;

            float dy1 = ya[1] - ya[0], dy2 = ya[2] - ya[0];
            float dx1 = xa[1] - xa[0], dx2 = xa[2] - xa[0];
            float g0 = ya[1] * xa[2] - ya[2] * xa[1];
            float g1 = ya[0] * xa[2] - ya[2] * xa[0];
            float g2 = ya[0] * xa[1] - ya[1] * xa[0];
            float inv3 = 1.0f / D012;

            float du1 = ru1 - ru0, du2 = ru2 - ru0;
            float dv1 = rv1 - rv0, dv2 = rv2 - rv0;

            float* so = sout + tid * (SPT * 9) + s * 9;
            so[0] = (du1 * dx2 - du2 * dx1) * inv3;
            so[1] = (dy1 * du2 - dy2 * du1) * inv3;
            so[2] = (ru0 * g0 - ru1 * g1 + ru2 * g2) * inv3;
            so[3] = (dv1 * dx2 - dv2 * dx1) * inv3;
            so[4] = (dy1 * dv2 - dy2 * dv1) * inv3;
            so[5] = (rv0 * g0 - rv1 * g1 + rv2 * g2) * inv3;
            so[6] = h6;
            so[7] = h7;
            so[8] = 1.0f;
        }
    } else {
        // tail (only when B % SPB != 0)
#pragma unroll
        for (int v = 0; v < SPT * 9; ++v) sout[tid * (SPT * 9) + v] = 0.f;
    }

    // ---- NO block barrier: each wave stores only its OWN staged region.
    //      (intra-wave ds_write -> ds_read ordering via compiler lgkmcnt) ----
    // wave w's region: samples [w*128, w*128+128) of this block
    // floats: 128*9 = 1152 per wave = 288 f32x4, 16B-aligned everywhere
    const size_t wbase = (size_t)blockIdx.x * SPB * 9 + (size_t)w * (128 * 9);  // floats
    const size_t total = (size_t)B * 9;
    const f32x4* s4w = reinterpret_cast<const f32x4*>(sout + (size_t)w * (128 * 9));
    if (wbase + 1152 <= total) {
        f32x4* out4w = reinterpret_cast<f32x4*>(out + wbase);
#pragma unroll
        for (int r = 0; r < 5; ++r) {
            int v = lane + r * 64;
            if (v < 288) out4w[v] = s4w[v];   // r<4 always true; r==4 -> half wave
        }
    } else {
        for (int v = lane; v < 1152; v += 64) {
            size_t g = wbase + v;
            if (g < total) out[g] = sout[(size_t)w * 1152 + v];
        }
    }
}

extern "C" void kernel_launch(void* const* d_in, const int* in_sizes, int n_in,
                              void* d_out, int out_size, void* d_ws, size_t ws_size,
                              hipStream_t stream) {
    const float* corners = (const float*)d_in[0];  // (8, B) float32
    const float* h4pt    = (const float*)d_in[1];  // (B, 8) float32
    float* out = (float*)d_out;                    // (B, 3, 3) float32
    const int B = in_sizes[0] / 8;
    const int grid = (B + SPB - 1) / SPB;
    dlt_solve_kernel<<<grid, BLK, 0, stream>>>(corners, h4pt, out, B);
}